// Round 4
// baseline (431.559 us; speedup 1.0000x reference)
//
#include <hip/hip_runtime.h>

// MS-Deformable Attention, MI355X gfx950.
// Pipeline: prep(weights->bf16,[N][K]) ; v=value@Wv (bf16 MFMA, out bf16)
//           p=query@[Woff|Wattn] (bf16 MFMA, out fp32, N padded to 128)
//           fused: sampling -> LDS tile -> out-proj GEMM (+bias+residual)
// R3: fused sample+outproj: kills 80MB ws_o round trip + 1 dispatch; sampling
//     remapped to 1 thread per (q,h) (was 4, with 4x redundant coord math).

typedef float  f4  __attribute__((ext_vector_type(4)));
typedef float  fx4 __attribute__((ext_vector_type(4)));
typedef short  s8  __attribute__((ext_vector_type(8)));
typedef short  s4  __attribute__((ext_vector_type(4)));

#define KDIM    256
#define NVPIX   40000
#define GH      200
#define GW      200
#define LDP     68          // gemm_k LDS row pitch (shorts): 64 data + 4 pad
#define SMPP    264         // fused sample-tile pitch (shorts): 256 + 8 pad
#define BSP     36          // fused B-staging pitch (shorts): 32 + 4 pad

__device__ __forceinline__ short f2bf(float f) {
  union { float f; unsigned u; } v; v.f = f;
  unsigned r = v.u + 0x7fffu + ((v.u >> 16) & 1u);   // round-to-nearest-even
  return (short)(r >> 16);
}
__device__ __forceinline__ float bf2f(unsigned short h) {
  union { unsigned u; float f; } v; v.u = ((unsigned)h) << 16; return v.f;
}

// ---------------------------------------------------------------- prep ----
__global__ void prep_k(const float* __restrict__ Wv, const float* __restrict__ Wo,
                       const float* __restrict__ Woff, const float* __restrict__ Wattn,
                       const float* __restrict__ boff, const float* __restrict__ battn,
                       unsigned short* __restrict__ Wv_t, unsigned short* __restrict__ Wo_t,
                       unsigned short* __restrict__ Wp_t, float* __restrict__ bp)
{
  int i = blockIdx.x * 256 + threadIdx.x;
  if (i < 65536) {
    int n = i >> 8, k = i & 255;
    Wv_t[i] = (unsigned short)f2bf(Wv[k * 256 + n]);
  } else if (i < 131072) {
    int j = i - 65536; int n = j >> 8, k = j & 255;
    Wo_t[j] = (unsigned short)f2bf(Wo[k * 256 + n]);
  } else if (i < 163840) {
    int j = i - 131072; int n = j >> 8, k = j & 255;
    float val = (n < 64) ? Woff[k * 64 + n] : ((n < 96) ? Wattn[k * 32 + (n - 64)] : 0.f);
    Wp_t[j] = (unsigned short)f2bf(val);
  } else if (i < 163968) {
    int j = i - 163840;
    bp[j] = (j < 64) ? boff[j] : ((j < 96) ? battn[j - 64] : 0.f);
  }
}

// ---------------------------------------------------------------- GEMM ----
// (v-proj and proj only now.) C[M,N] = A[M,K=256](f32) * B^T + bias.
// 128x128 tile, BK=64, register-prefetch pipeline.
template<int CBF>
__global__ __launch_bounds__(256)
void gemm_k(const float* __restrict__ Ap, const unsigned short* __restrict__ Bt,
            const float* __restrict__ bias, void* __restrict__ Cp, int N)
{
  __shared__ short As[128 * LDP];
  __shared__ short Bs[128 * LDP];
  const int t  = threadIdx.x;
  const int m0 = blockIdx.x * 128;
  const int n0 = blockIdx.y * 128;
  const int lane = t & 63;
  const int w  = t >> 6;
  const int wm = (w >> 1) * 64;
  const int wn = (w & 1) * 64;
  const int fr = lane & 15;
  const int quad = lane >> 4;

  fx4 acc[4][4];
  #pragma unroll
  for (int i = 0; i < 4; i++)
    #pragma unroll
    for (int j = 0; j < 4; j++) { fx4 z = {0.f, 0.f, 0.f, 0.f}; acc[i][j] = z; }

  f4 pa[8];    // A prefetch: 128x64 f32 tile, 8 f4 per thread
  s8 pb[4];    // B prefetch

  auto loadA = [&](int k0) {
    const float* base = Ap + (size_t)m0 * KDIM + k0;
    #pragma unroll
    for (int j = 0; j < 8; j++) {
      int id = t + j * 256;
      int row = id >> 4, kp = (id & 15) * 4;
      pa[j] = *(const f4*)(base + (size_t)row * KDIM + kp);
    }
  };
  auto loadB = [&](int k0) {
    const unsigned short* base = Bt + (size_t)n0 * KDIM + k0;
    #pragma unroll
    for (int j = 0; j < 4; j++) {
      int id = t + j * 256;
      int row = id >> 3, kp = (id & 7) * 8;
      pb[j] = *(const s8*)(base + (size_t)row * KDIM + kp);
    }
  };
  auto storeAB = [&]() {
    #pragma unroll
    for (int j = 0; j < 8; j++) {
      int id = t + j * 256;
      int row = id >> 4, kp = (id & 15) * 4;
      s4 c;
      #pragma unroll
      for (int e = 0; e < 4; e++) c[e] = f2bf(pa[j][e]);
      *(s4*)(&As[row * LDP + kp]) = c;
    }
    #pragma unroll
    for (int j = 0; j < 4; j++) {
      int id = t + j * 256;
      int row = id >> 3, kp = (id & 7) * 8;
      *(s8*)(&Bs[row * LDP + kp]) = pb[j];
    }
  };

  loadA(0); loadB(0);
  #pragma unroll
  for (int it = 0; it < 4; ++it) {
    __syncthreads();
    storeAB();
    __syncthreads();
    if (it < 3) { loadA((it + 1) * 64); loadB((it + 1) * 64); }
    #pragma unroll
    for (int kk = 0; kk < 2; kk++) {
      s8 afr[4], bfr[4];
      #pragma unroll
      for (int i = 0; i < 4; i++)
        afr[i] = *(const s8*)(&As[(wm + i * 16 + fr) * LDP + kk * 32 + quad * 8]);
      #pragma unroll
      for (int i = 0; i < 4; i++)
        bfr[i] = *(const s8*)(&Bs[(wn + i * 16 + fr) * LDP + kk * 32 + quad * 8]);
      #pragma unroll
      for (int i = 0; i < 4; i++)
        #pragma unroll
        for (int j = 0; j < 4; j++)
          acc[i][j] = __builtin_amdgcn_mfma_f32_16x16x32_bf16(afr[i], bfr[j], acc[i][j], 0, 0, 0);
    }
  }

  // Epilogue: C/D layout col=lane&15, row=quad*4+reg (verified m89/m91).
  #pragma unroll
  for (int i = 0; i < 4; i++) {
    const int mbase = m0 + wm + i * 16 + quad * 4;
    #pragma unroll
    for (int j = 0; j < 4; j++) {
      const int n = n0 + wn + j * 16 + fr;
      const float bn = bias[n];
      #pragma unroll
      for (int r = 0; r < 4; r++) {
        const size_t m = (size_t)(mbase + r);
        float v = acc[i][j][r] + bn;
        if (CBF) ((unsigned short*)Cp)[m * (size_t)N + n] = (unsigned short)f2bf(v);
        else     ((float*)Cp)[m * (size_t)N + n] = v;
      }
    }
  }
}

// ------------------------------------------------- fused sample+outproj ----
// Block = 64 queries, 256 threads.
// Phase A: task=(qi,h), 2 iters; softmax + 4pt bilinear gather of 32 ch;
//          result written bf16 into smp[64][SMPP] (the GEMM A-tile).
// Phase B: out[64,256] = smp @ Wo^T + bo + query. BK=32, 8 iters, Wo tile
//          reg-prefetched into Bs. Wave w owns m-rows w*16..w*16+15, all n.
__global__ __launch_bounds__(256)
void fused_k(const unsigned short* __restrict__ v, const float* __restrict__ p,
             const float* __restrict__ ref, const unsigned short* __restrict__ Wo_t,
             const float* __restrict__ bo, const float* __restrict__ query,
             float* __restrict__ out)
{
  __shared__ short smp[64 * SMPP];
  __shared__ short Bs[256 * BSP];
  const int t  = threadIdx.x;
  const int q0 = blockIdx.x * 64;

  // ---------------- Phase A: sampling ----------------
  #pragma unroll
  for (int itA = 0; itA < 2; ++itA) {
    const int id = t + itA * 256;
    const int qi = id >> 3;
    const int h  = id & 7;
    const int q  = q0 + qi;
    const int b  = (q >= 40000) ? 1 : 0;
    const float* pq = p + (size_t)q * 128;
    const f4 off0 = *(const f4*)(pq + h * 8);
    const f4 off1 = *(const f4*)(pq + h * 8 + 4);
    const f4 lg   = *(const f4*)(pq + 64 + h * 4);
    const float rx = ref[(size_t)q * 2], ry = ref[(size_t)q * 2 + 1];

    const float mx = fmaxf(fmaxf(lg[0], lg[1]), fmaxf(lg[2], lg[3]));
    const float e0 = __expf(lg[0] - mx), e1 = __expf(lg[1] - mx);
    const float e2 = __expf(lg[2] - mx), e3 = __expf(lg[3] - mx);
    const float inv = 1.f / (e0 + e1 + e2 + e3);
    const float aws[4] = {e0 * inv, e1 * inv, e2 * inv, e3 * inv};
    const float offs[8] = {off0[0], off0[1], off0[2], off0[3],
                           off1[0], off1[1], off1[2], off1[3]};

    const unsigned short* vb = v + (size_t)b * NVPIX * 256 + h * 32;

    float acc[32];
    #pragma unroll
    for (int e = 0; e < 32; e++) acc[e] = 0.f;

    #pragma unroll
    for (int pt = 0; pt < 4; ++pt) {
      const float px = rx * 200.f + offs[pt * 2]     - 0.5f;
      const float py = ry * 200.f + offs[pt * 2 + 1] - 0.5f;
      const float x0f = floorf(px), y0f = floorf(py);
      const int ix = (int)x0f, iy = (int)y0f;
      const float fx = px - x0f, fy = py - y0f;
      const float a = aws[pt];
      const float vx0 = (ix >= 0 && ix < GW) ? 1.f : 0.f;
      const float vx1 = (ix + 1 >= 0 && ix + 1 < GW) ? 1.f : 0.f;
      const float vy0 = (iy >= 0 && iy < GH) ? 1.f : 0.f;
      const float vy1 = (iy + 1 >= 0 && iy + 1 < GH) ? 1.f : 0.f;
      const float w00 = a * (1.f - fx) * (1.f - fy) * vx0 * vy0;
      const float w01 = a * fx * (1.f - fy) * vx1 * vy0;
      const float w10 = a * (1.f - fx) * fy * vx0 * vy1;
      const float w11 = a * fx * fy * vx1 * vy1;
      const int ix0c = min(max(ix, 0), GW - 1);
      const int ix1c = min(max(ix + 1, 0), GW - 1);
      const int iy0c = min(max(iy, 0), GH - 1);
      const int iy1c = min(max(iy + 1, 0), GH - 1);
      const unsigned short* c00 = vb + ((long)iy0c * GW + ix0c) * 256;
      const unsigned short* c01 = vb + ((long)iy0c * GW + ix1c) * 256;
      const unsigned short* c10 = vb + ((long)iy1c * GW + ix0c) * 256;
      const unsigned short* c11 = vb + ((long)iy1c * GW + ix1c) * 256;
      #pragma unroll
      for (int g = 0; g < 4; g++) {           // 8-channel groups
        s8 g00 = *(const s8*)(c00 + g * 8);
        s8 g01 = *(const s8*)(c01 + g * 8);
        s8 g10 = *(const s8*)(c10 + g * 8);
        s8 g11 = *(const s8*)(c11 + g * 8);
        #pragma unroll
        for (int e = 0; e < 8; e++) {
          acc[g * 8 + e] += w00 * bf2f((unsigned short)g00[e])
                          + w01 * bf2f((unsigned short)g01[e])
                          + w10 * bf2f((unsigned short)g10[e])
                          + w11 * bf2f((unsigned short)g11[e]);
        }
      }
    }
    #pragma unroll
    for (int g = 0; g < 4; g++) {
      s8 res;
      #pragma unroll
      for (int e = 0; e < 8; e++) res[e] = f2bf(acc[g * 8 + e]);
      *(s8*)(&smp[qi * SMPP + h * 32 + g * 8]) = res;
    }
  }

  // ---------------- Phase B: out-proj GEMM ----------------
  const int lane = t & 63;
  const int w    = t >> 6;
  const int fr   = lane & 15;
  const int quad = lane >> 4;

  fx4 oacc[16];
  #pragma unroll
  for (int j = 0; j < 16; j++) { fx4 z = {0.f, 0.f, 0.f, 0.f}; oacc[j] = z; }

  s8 pbB[4];
  auto loadB = [&](int k0) {
    #pragma unroll
    for (int j = 0; j < 4; j++) {
      int id = t + j * 256;
      int row = id >> 2, kg = id & 3;
      pbB[j] = *(const s8*)(Wo_t + (size_t)row * KDIM + k0 + kg * 8);
    }
  };
  auto storeB = [&]() {
    #pragma unroll
    for (int j = 0; j < 4; j++) {
      int id = t + j * 256;
      int row = id >> 2, kg = id & 3;
      *(s8*)(&Bs[row * BSP + kg * 8]) = pbB[j];
    }
  };

  loadB(0);
  #pragma unroll
  for (int it = 0; it < 8; ++it) {
    storeB();
    __syncthreads();               // first iter: also covers smp writes
    if (it < 7) loadB((it + 1) * 32);
    const s8 afr = *(const s8*)(&smp[(w * 16 + fr) * SMPP + it * 32 + quad * 8]);
    #pragma unroll
    for (int j = 0; j < 16; j++) {
      const s8 bfr = *(const s8*)(&Bs[(j * 16 + fr) * BSP + quad * 8]);
      oacc[j] = __builtin_amdgcn_mfma_f32_16x16x32_bf16(afr, bfr, oacc[j], 0, 0, 0);
    }
    if (it < 7) __syncthreads();   // all Bs reads done before next storeB
  }

  // Epilogue: rows m = q0 + w*16 + quad*4 + r ; cols n = j*16 + fr.
  #pragma unroll
  for (int j = 0; j < 16; j++) {
    const int n = j * 16 + fr;
    const float bn = bo[n];
    #pragma unroll
    for (int r = 0; r < 4; r++) {
      const size_t m = (size_t)(q0 + w * 16 + quad * 4 + r);
      out[m * 256 + n] = oacc[j][r] + bn + query[m * 256 + n];
    }
  }
}

// --------------------------------------------------------------- launch ----
extern "C" void kernel_launch(void* const* d_in, const int* in_sizes, int n_in,
                              void* d_out, int out_size, void* d_ws, size_t ws_size,
                              hipStream_t stream)
{
  const float* query = (const float*)d_in[0];
  const float* value = (const float*)d_in[1];
  const float* refp  = (const float*)d_in[2];
  // d_in[3] spatial_shapes: compile-time (200,200)
  const float* Wv    = (const float*)d_in[4];
  const float* bv    = (const float*)d_in[5];
  const float* Woff  = (const float*)d_in[6];
  const float* boff  = (const float*)d_in[7];
  const float* Wattn = (const float*)d_in[8];
  const float* battn = (const float*)d_in[9];
  const float* Wo    = (const float*)d_in[10];
  const float* bo    = (const float*)d_in[11];

  char* ws = (char*)d_ws;
  unsigned short* ws_v = (unsigned short*)ws;                  // 80000*256 bf16 = 40.96 MB
  float*          ws_p = (float*)(ws + 40960000);              // 80000*128 f32  = 40.96 MB
  unsigned short* Wv_t = (unsigned short*)(ws + 122880000);    // 256*256 bf16
  unsigned short* Wo_t = Wv_t + 65536;                         // 256*256 bf16
  unsigned short* Wp_t = Wo_t + 65536;                         // 128*256 bf16
  float*          bp   = (float*)(Wp_t + 32768);               // 128 f32

  hipLaunchKernelGGL(prep_k, dim3(641), dim3(256), 0, stream,
                     Wv, Wo, Woff, Wattn, boff, battn, Wv_t, Wo_t, Wp_t, bp);
  // v = value @ Wv + bv  -> bf16
  hipLaunchKernelGGL((gemm_k<1>), dim3(625, 2), dim3(256), 0, stream,
                     value, Wv_t, bv, (void*)ws_v, 256);
  // p = query @ [Woff|Wattn|0] + bp -> f32 (stride 128)
  hipLaunchKernelGGL((gemm_k<0>), dim3(625, 1), dim3(256), 0, stream,
                     query, Wp_t, bp, (void*)ws_p, 128);
  // fused sampling + out-proj (+bias+residual)
  hipLaunchKernelGGL(fused_k, dim3(1250), dim3(256), 0, stream,
                     ws_v, ws_p, refp, Wo_t, bo, query, (float*)d_out);
}